// Round 11
// baseline (208.215 us; speedup 1.0000x reference)
//
#include <hip/hip_runtime.h>

// GIN 2-layer forward — CSR counting sort + bf16 gather tables + fused MFMA MLP.
// Pipeline (8 dispatches):
//   prep:      w1t/w2t bf16 transposed tables + zero binCnt
//   cvt_hist:  xh = bf16(node_emb)  ||  LDS-histogram dst>>8   (grid-partitioned)
//   scan_bins -> partition (EPB 16384, stream-reread) -> bin_finalize
//   agg1h = bf16( xh[self] + gather(xh) )        [gather_l1, 16/8-deep]
//   mlp_fused: h = relu(agg1h@W1+b1) in LDS; gh = bf16(h@W2)   [MFMA 16x16x32]
//   out = b2 + gh[self] + gather(gh)  (f32)      [gather_l2]
// (W2 folded before aggregation-2: (A h + h) W2 + b2 = A(hW2) + hW2 + b2.)
// R5: don't fuse gather into GEMM (occupancy). R6: gather cache-BW bound ->
// bf16 tables. R7-R9: f32 vector GEMM trapped (LDS rate / barriers) -> MFMA.
// R10: build+glue is ~1/3 of runtime -> this round: fewer launches, longer
// partition write runs, self-terms from bf16 tables, deeper gather MLP.

#define EPB 4096      // edges per hist block
#define EPB2 16384    // edges per partition block
#define CAP 6144      // LDS staging cap in bin_finalize
#define LDST 136      // LDS h row stride in u16 (272 B, 16B-aligned)

typedef __attribute__((ext_vector_type(8))) short bf16x8;
typedef __attribute__((ext_vector_type(4))) float f32x4;

__device__ __forceinline__ unsigned short f2b(float f) {   // RNE f32->bf16
    unsigned u = __float_as_uint(f);
    return (unsigned short)((u + 0x7fffu + ((u >> 16) & 1u)) >> 16);
}
__device__ __forceinline__ unsigned pk(float a, float b) {
    return (unsigned)f2b(a) | ((unsigned)f2b(b) << 16);
}
__device__ __forceinline__ float bl(unsigned u) { return __uint_as_float(u << 16); }
__device__ __forceinline__ float bh(unsigned u) { return __uint_as_float(u & 0xffff0000u); }

// W1t [128c][64k] bf16, W2t [64c][128k] bf16, zero binCnt. grid 66x256.
__global__ void prep(const float* __restrict__ W1, const float* __restrict__ W2,
                     unsigned short* __restrict__ w1t, unsigned short* __restrict__ w2t,
                     int* __restrict__ binCnt) {
    int i = blockIdx.x * 256 + threadIdx.x;
    if (i < 8192) {
        int c = i >> 6, k = i & 63;
        w1t[i] = f2b(W1[k * 128 + c]);
    } else if (i < 16384) {
        int j = i - 8192;
        int c = j >> 7, k = j & 127;
        w2t[j] = f2b(W2[k * 64 + c]);
    } else if (i < 16384 + 512) {
        binCnt[i - 16384] = 0;
    }
}

// blocks [0,nCvt): xh = bf16(x). blocks [nCvt, nCvt+nHist): LDS hist of dst>>8.
__global__ __launch_bounds__(256) void cvt_hist(const float4* __restrict__ x4,
                                                uint2* __restrict__ xh, int n16,
                                                const int* __restrict__ dst,
                                                int* __restrict__ binCnt,
                                                int ne, int nbins, int nCvt) {
    if ((int)blockIdx.x < nCvt) {
        int i = blockIdx.x * 256 + threadIdx.x;
        if (i < n16) {
            float4 v = x4[i];
            xh[i] = make_uint2(pk(v.x, v.y), pk(v.z, v.w));
        }
        return;
    }
    __shared__ int h[512];
    int t = threadIdx.x;
    for (int i = t; i < nbins; i += 256) h[i] = 0;
    __syncthreads();
    int eb = ((int)blockIdx.x - nCvt) * EPB;
#pragma unroll
    for (int i = 0; i < 16; ++i) {
        int e = eb + t + i * 256;
        if (e < ne) atomicAdd(&h[dst[e] >> 8], 1);
    }
    __syncthreads();
    for (int i = t; i < nbins; i += 256) if (h[i]) atomicAdd(&binCnt[i], h[i]);
}

__global__ __launch_bounds__(512) void scan_bins(const int* __restrict__ binCnt,
                                                 int* __restrict__ binOff, int* __restrict__ binCur,
                                                 int* __restrict__ off, int nbins, int n, int ne) {
    __shared__ int s[512];
    int t = threadIdx.x;
    int v = (t < nbins) ? binCnt[t] : 0;
    s[t] = v;
    __syncthreads();
    for (int o = 1; o < 512; o <<= 1) {
        int u = (t >= o) ? s[t - o] : 0;
        __syncthreads();
        s[t] += u;
        __syncthreads();
    }
    if (t < nbins) { int b = s[t] - v; binOff[t] = b; binCur[t] = b; }
    if (t == 0) { binOff[nbins] = ne; off[n] = ne; }
}

// EPB2 edges/block, stream-reread: pass A hist (dst), flush to binCur for
// block bases, pass B re-read src+dst and scatter packed (src<<8|dstLocal).
__global__ __launch_bounds__(256) void partition(const int* __restrict__ src,
                                                 const int* __restrict__ dst,
                                                 int* __restrict__ binCur,
                                                 unsigned* __restrict__ part, int ne, int nbins) {
    __shared__ int h[512];
    __shared__ int base[512];
    int t = threadIdx.x;
    for (int i = t; i < nbins; i += 256) h[i] = 0;
    __syncthreads();
    int eb = blockIdx.x * EPB2;
    for (int i = t; i < EPB2; i += 256) {
        int e = eb + i;
        if (e < ne) atomicAdd(&h[dst[e] >> 8], 1);
    }
    __syncthreads();
    for (int i = t; i < nbins; i += 256) base[i] = h[i] ? atomicAdd(&binCur[i], h[i]) : 0;
    __syncthreads();
    for (int i = t; i < nbins; i += 256) h[i] = 0;   // reuse as local cursor
    __syncthreads();
    for (int i = t; i < EPB2; i += 256) {
        int e = eb + i;
        if (e < ne) {
            int d = dst[e];
            int b = d >> 8;
            int p = atomicAdd(&h[b], 1);
            part[base[b] + p] = ((unsigned)src[e] << 8) | (unsigned)(d & 255);
        }
    }
}

__global__ __launch_bounds__(256) void bin_finalize(const unsigned* __restrict__ part,
                                                    const int* __restrict__ binOff,
                                                    int* __restrict__ off, int* __restrict__ perm,
                                                    int n, int nbins) {
    __shared__ unsigned st[CAP];
    __shared__ int cnt[256], ex[256], cur[256];
    int b = blockIdx.x;
    int t = threadIdx.x;
    int e0 = binOff[b], e1 = binOff[b + 1];
    int m = e1 - e0;
    int nb0 = b << 8;
    int nn = min(256, n - nb0);
    cnt[t] = 0;
    __syncthreads();
    bool staged = (m <= CAP);
    if (staged) {
        for (int i = t; i < m; i += 256) { unsigned v = part[e0 + i]; st[i] = v; atomicAdd(&cnt[v & 255u], 1); }
    } else {
        for (int i = t; i < m; i += 256) { unsigned v = part[e0 + i]; atomicAdd(&cnt[v & 255u], 1); }
    }
    __syncthreads();
    int v = cnt[t];
    ex[t] = v;
    __syncthreads();
    for (int o = 1; o < 256; o <<= 1) {
        int u = (t >= o) ? ex[t - o] : 0;
        __syncthreads();
        ex[t] += u;
        __syncthreads();
    }
    int excl = ex[t] - v;
    if (t < nn) off[nb0 + t] = e0 + excl;
    cur[t] = excl;
    __syncthreads();
    if (staged) {
        for (int i = t; i < m; i += 256) {
            unsigned w = st[i];
            int p = atomicAdd(&cur[w & 255u], 1);
            perm[e0 + p] = (int)(w >> 8);
        }
    } else {
        for (int i = t; i < m; i += 256) {
            unsigned w = part[e0 + i];
            int p = atomicAdd(&cur[w & 255u], 1);
            perm[e0 + p] = (int)(w >> 8);
        }
    }
}

// acc = bf16_table[self] + sum_{e in CSR(i)} bf16_table[perm[e]]
// 16 lanes/node, 16 nodes/block; 16-deep then 8-deep then scalar edge batches.
#define GATHER_BODY                                                               \
    int t = threadIdx.x;                                                          \
    int node = blockIdx.x * 16 + (t >> 4);                                        \
    int c = t & 15;                                                               \
    if (node >= n) return;                                                        \
    int beg = off[node], end = off[node + 1];                                     \
    uint2 sv = xh[(size_t)node * 16 + c];                                         \
    float4 acc = make_float4(bl(sv.x), bh(sv.x), bl(sv.y), bh(sv.y));             \
    int e = beg;                                                                  \
    for (; e + 16 <= end; e += 16) {                                              \
        uint2 v[16];                                                              \
        _Pragma("unroll")                                                         \
        for (int j = 0; j < 16; ++j) v[j] = xh[(size_t)perm[e + j] * 16 + c];     \
        _Pragma("unroll")                                                         \
        for (int j = 0; j < 16; ++j) {                                            \
            acc.x += bl(v[j].x); acc.y += bh(v[j].x);                             \
            acc.z += bl(v[j].y); acc.w += bh(v[j].y);                             \
        }                                                                         \
    }                                                                             \
    for (; e + 8 <= end; e += 8) {                                                \
        uint2 v[8];                                                               \
        _Pragma("unroll")                                                         \
        for (int j = 0; j < 8; ++j) v[j] = xh[(size_t)perm[e + j] * 16 + c];      \
        _Pragma("unroll")                                                         \
        for (int j = 0; j < 8; ++j) {                                             \
            acc.x += bl(v[j].x); acc.y += bh(v[j].x);                             \
            acc.z += bl(v[j].y); acc.w += bh(v[j].y);                             \
        }                                                                         \
    }                                                                             \
    for (; e < end; ++e) {                                                        \
        uint2 v = xh[(size_t)perm[e] * 16 + c];                                   \
        acc.x += bl(v.x); acc.y += bh(v.x); acc.z += bl(v.y); acc.w += bh(v.y);   \
    }

// layer 1: emit bf16 (feeds MFMA A-fragments)
__global__ __launch_bounds__(256) void gather_l1(const uint2* __restrict__ xh,
                                                 const int* __restrict__ off,
                                                 const int* __restrict__ perm,
                                                 uint2* __restrict__ outh, int n) {
    GATHER_BODY
    outh[(size_t)node * 16 + c] = make_uint2(pk(acc.x, acc.y), pk(acc.z, acc.w));
}

// layer 2: emit f32 with bias (the final output)
__global__ __launch_bounds__(256) void gather_l2(const uint2* __restrict__ xh,
                                                 const float* __restrict__ bias,
                                                 const int* __restrict__ off,
                                                 const int* __restrict__ perm,
                                                 float4* __restrict__ out4, int n) {
    GATHER_BODY
    float4 bb = reinterpret_cast<const float4*>(bias)[c];
    acc.x += bb.x; acc.y += bb.y; acc.z += bb.z; acc.w += bb.w;
    out4[(size_t)node * 16 + c] = acc;
}

// Fused MLP via MFMA 16x16x32 bf16. 4 waves, 128 rows/block, 32 rows/wave.
// Phase 1: h=relu(A@W1+b1) -> LDS bf16 (wave-private rows, no __syncthreads).
// Phase 2: gh = bf16(h@W2). b2 is applied by gather_l2.
// Fragment layouts (guide m89-verified): A: row=l&15, k=(l>>4)*8+j;
// B: col=l&15, k=(l>>4)*8+j (W stored transposed [col][k]);
// D: col=l&15, row=(l>>4)*4+reg.
__global__ __launch_bounds__(256) void mlp_fused(const unsigned short* __restrict__ ah,
                                                 const unsigned short* __restrict__ w1t,
                                                 const float* __restrict__ b1,
                                                 const unsigned short* __restrict__ w2t,
                                                 unsigned short* __restrict__ gh, int n) {
    __shared__ unsigned short hl[128][LDST];   // 34.8 KiB
    int t = threadIdx.x;
    int w = t >> 6;
    int l = t & 63;
    int lr = l & 15;
    int lg = l >> 4;
    int row0 = blockIdx.x * 128 + w * 32;

    // ---- phase 1: h = relu(agg1h @ W1 + b1) -> LDS ----
    bf16x8 b1f[8][2];
#pragma unroll
    for (int ct = 0; ct < 8; ++ct)
#pragma unroll
        for (int kc = 0; kc < 2; ++kc)
            b1f[ct][kc] = *reinterpret_cast<const bf16x8*>(
                w1t + (size_t)(ct * 16 + lr) * 64 + kc * 32 + lg * 8);
    float bias1[8];
#pragma unroll
    for (int ct = 0; ct < 8; ++ct) bias1[ct] = b1[ct * 16 + lr];

#pragma unroll
    for (int rt = 0; rt < 2; ++rt) {
        int arow = row0 + rt * 16 + lr;
        if (arow > n - 1) arow = n - 1;
        bf16x8 a0 = *reinterpret_cast<const bf16x8*>(ah + (size_t)arow * 64 + lg * 8);
        bf16x8 a1 = *reinterpret_cast<const bf16x8*>(ah + (size_t)arow * 64 + 32 + lg * 8);
        int lrow = w * 32 + rt * 16 + lg * 4;
#pragma unroll
        for (int ct = 0; ct < 8; ++ct) {
            f32x4 acc = {0.f, 0.f, 0.f, 0.f};
            acc = __builtin_amdgcn_mfma_f32_16x16x32_bf16(a0, b1f[ct][0], acc, 0, 0, 0);
            acc = __builtin_amdgcn_mfma_f32_16x16x32_bf16(a1, b1f[ct][1], acc, 0, 0, 0);
#pragma unroll
            for (int r = 0; r < 4; ++r) {
                float v = fmaxf(acc[r] + bias1[ct], 0.f);
                hl[lrow + r][ct * 16 + lr] = f2b(v);
            }
        }
    }

    // ---- phase 2: g = h @ W2 (same-wave LDS reuse; compiler inserts waits) ----
    bf16x8 b2f[4][4];
#pragma unroll
    for (int ct = 0; ct < 4; ++ct)
#pragma unroll
        for (int kc = 0; kc < 4; ++kc)
            b2f[ct][kc] = *reinterpret_cast<const bf16x8*>(
                w2t + (size_t)(ct * 16 + lr) * 128 + kc * 32 + lg * 8);

#pragma unroll
    for (int rt = 0; rt < 2; ++rt) {
        int lrow = w * 32 + rt * 16 + lr;
        f32x4 acc[4];
#pragma unroll
        for (int ct = 0; ct < 4; ++ct) acc[ct] = (f32x4){0.f, 0.f, 0.f, 0.f};
#pragma unroll
        for (int kc = 0; kc < 4; ++kc) {
            bf16x8 a = *reinterpret_cast<const bf16x8*>(&hl[lrow][kc * 32 + lg * 8]);
#pragma unroll
            for (int ct = 0; ct < 4; ++ct)
                acc[ct] = __builtin_amdgcn_mfma_f32_16x16x32_bf16(a, b2f[ct][kc], acc[ct], 0, 0, 0);
        }
        int orow = row0 + rt * 16 + lg * 4;
#pragma unroll
        for (int ct = 0; ct < 4; ++ct) {
#pragma unroll
            for (int r = 0; r < 4; ++r) {
                int row = orow + r;
                if (row < n) gh[(size_t)row * 64 + ct * 16 + lr] = f2b(acc[ct][r]);
            }
        }
    }
}

extern "C" void kernel_launch(void* const* d_in, const int* in_sizes, int n_in,
                              void* d_out, int out_size, void* d_ws, size_t ws_size,
                              hipStream_t stream) {
    const float* node_emb = (const float*)d_in[0];
    const float* W1 = (const float*)d_in[1];
    const float* b1 = (const float*)d_in[2];
    const float* W2 = (const float*)d_in[3];
    const float* b2 = (const float*)d_in[4];
    const int*   ei = (const int*)d_in[5];
    int n  = in_sizes[0] / 64;
    int ne = in_sizes[5] / 2;
    const int* src = ei;
    const int* dst = ei + ne;
    float* out = (float*)d_out;

    int nbins = (n + 255) >> 8;   // 391

    // workspace layout (~56 MB, no aliasing)
    char* ws = (char*)d_ws;
    const size_t MB = 1024 * 1024;
    uint2*          agg1h = (uint2*)ws;                          // n*64 bf16 (12.8 MB)
    uint2*          gh    = (uint2*)(ws + 13 * MB);              // n*64 bf16 (12.8 MB)
    uint2*          xh    = (uint2*)(ws + 26 * MB);              // n*64 bf16 (12.8 MB)
    unsigned*       part  = (unsigned*)(ws + 39 * MB);           // ne u32 (6.4 MB)
    unsigned short* w1t   = (unsigned short*)(ws + 46 * MB);     // 16 KB
    unsigned short* w2t   = (unsigned short*)(ws + 46 * MB + 65536);
    int* off    = (int*)(ws + 47 * MB);                          // (n+1)*4
    int* perm   = (int*)(ws + 48 * MB);                          // ne*4 (6.4 MB)
    int* binCnt = (int*)(ws + 55 * MB);
    int* binOff = (int*)(ws + 55 * MB + 4096);
    int* binCur = (int*)(ws + 55 * MB + 8192);

    int nCvt  = (n * 16 + 255) / 256;          // 6250
    int nHist = (ne + EPB - 1) / EPB;          // 391
    int nPart = (ne + EPB2 - 1) / EPB2;        // 98

    prep<<<66, 256, 0, stream>>>(W1, W2, w1t, w2t, binCnt);
    cvt_hist<<<nCvt + nHist, 256, 0, stream>>>((const float4*)node_emb, xh, n * 16,
                                               dst, binCnt, ne, nbins, nCvt);
    scan_bins<<<1, 512, 0, stream>>>(binCnt, binOff, binCur, off, nbins, n, ne);
    partition<<<nPart, 256, 0, stream>>>(src, dst, binCur, part, ne, nbins);
    bin_finalize<<<nbins, 256, 0, stream>>>(part, binOff, off, perm, n, nbins);

    gather_l1<<<(n + 15) / 16, 256, 0, stream>>>(xh, off, perm, agg1h, n);
    mlp_fused<<<(n + 127) / 128, 256, 0, stream>>>((const unsigned short*)agg1h, w1t, b1,
                                                   w2t, (unsigned short*)gh, n);
    gather_l2<<<(n + 15) / 16, 256, 0, stream>>>(gh, b2, off, perm, (float4*)out, n);
}

// Round 12
// 172.363 us; speedup vs baseline: 1.2080x; 1.2080x over previous
//
#include <hip/hip_runtime.h>

// GIN 2-layer forward — CSR counting sort + bf16 gather tables + fused MFMA MLP.
// Pipeline (8 dispatches):
//   prep:      w1t/w2t bf16 transposed tables + zero binCnt
//   cvt_hist:  xh = bf16(node_emb)  ||  LDS-histogram dst>>8   (grid-partitioned)
//   scan_bins -> partition (EPB 4096, 16-reg cache) -> bin_finalize
//   agg1h = bf16( xh[self] + gather(xh) )        [gather_l1, 16/8-deep]
//   mlp_fused: h = relu(agg1h@W1+b1) in LDS; gh = bf16(h@W2)   [MFMA 16x16x32]
//   out = b2 + gh[self] + gather(gh)  (f32)      [gather_l2]
// (W2 folded before aggregation-2: (A h + h) W2 + b2 = A(hW2) + hW2 + b2.)
// R5: don't fuse gather into GEMM (occupancy). R6: gather cache-BW bound ->
// bf16 tables. R7-R9: f32 vector GEMM trapped (LDS rate / barriers) -> MFMA.
// R11 lesson: EPB 16384 partition = 98 blocks = 3.5% occupancy = 80 µs; write-run
// length is worthless if the chip is idle. Reverted to EPB 4096 + reg cache.

#define EPB 4096      // edges per hist/partition block
#define CAP 6144      // LDS staging cap in bin_finalize
#define LDST 136      // LDS h row stride in u16 (272 B, 16B-aligned)

typedef __attribute__((ext_vector_type(8))) short bf16x8;
typedef __attribute__((ext_vector_type(4))) float f32x4;

__device__ __forceinline__ unsigned short f2b(float f) {   // RNE f32->bf16
    unsigned u = __float_as_uint(f);
    return (unsigned short)((u + 0x7fffu + ((u >> 16) & 1u)) >> 16);
}
__device__ __forceinline__ unsigned pk(float a, float b) {
    return (unsigned)f2b(a) | ((unsigned)f2b(b) << 16);
}
__device__ __forceinline__ float bl(unsigned u) { return __uint_as_float(u << 16); }
__device__ __forceinline__ float bh(unsigned u) { return __uint_as_float(u & 0xffff0000u); }

// W1t [128c][64k] bf16, W2t [64c][128k] bf16, zero binCnt. grid 66x256.
__global__ void prep(const float* __restrict__ W1, const float* __restrict__ W2,
                     unsigned short* __restrict__ w1t, unsigned short* __restrict__ w2t,
                     int* __restrict__ binCnt) {
    int i = blockIdx.x * 256 + threadIdx.x;
    if (i < 8192) {
        int c = i >> 6, k = i & 63;
        w1t[i] = f2b(W1[k * 128 + c]);
    } else if (i < 16384) {
        int j = i - 8192;
        int c = j >> 7, k = j & 127;
        w2t[j] = f2b(W2[k * 64 + c]);
    } else if (i < 16384 + 512) {
        binCnt[i - 16384] = 0;
    }
}

// blocks [0,nCvt): xh = bf16(x). blocks [nCvt, nCvt+nHist): LDS hist of dst>>8.
__global__ __launch_bounds__(256) void cvt_hist(const float4* __restrict__ x4,
                                                uint2* __restrict__ xh, int n16,
                                                const int* __restrict__ dst,
                                                int* __restrict__ binCnt,
                                                int ne, int nbins, int nCvt) {
    if ((int)blockIdx.x < nCvt) {
        int i = blockIdx.x * 256 + threadIdx.x;
        if (i < n16) {
            float4 v = x4[i];
            xh[i] = make_uint2(pk(v.x, v.y), pk(v.z, v.w));
        }
        return;
    }
    __shared__ int h[512];
    int t = threadIdx.x;
    for (int i = t; i < nbins; i += 256) h[i] = 0;
    __syncthreads();
    int eb = ((int)blockIdx.x - nCvt) * EPB;
#pragma unroll
    for (int i = 0; i < 16; ++i) {
        int e = eb + t + i * 256;
        if (e < ne) atomicAdd(&h[dst[e] >> 8], 1);
    }
    __syncthreads();
    for (int i = t; i < nbins; i += 256) if (h[i]) atomicAdd(&binCnt[i], h[i]);
}

__global__ __launch_bounds__(512) void scan_bins(const int* __restrict__ binCnt,
                                                 int* __restrict__ binOff, int* __restrict__ binCur,
                                                 int* __restrict__ off, int nbins, int n, int ne) {
    __shared__ int s[512];
    int t = threadIdx.x;
    int v = (t < nbins) ? binCnt[t] : 0;
    s[t] = v;
    __syncthreads();
    for (int o = 1; o < 512; o <<= 1) {
        int u = (t >= o) ? s[t - o] : 0;
        __syncthreads();
        s[t] += u;
        __syncthreads();
    }
    if (t < nbins) { int b = s[t] - v; binOff[t] = b; binCur[t] = b; }
    if (t == 0) { binOff[nbins] = ne; off[n] = ne; }
}

// R4-style: 16 edges/thread cached in regs; LDS hist; one global atomic per
// nonzero bin per block; LDS-cursor scatter of packed (src<<8|dstLocal).
__global__ __launch_bounds__(256) void partition(const int* __restrict__ src,
                                                 const int* __restrict__ dst,
                                                 int* __restrict__ binCur,
                                                 unsigned* __restrict__ part, int ne, int nbins) {
    __shared__ int h[512];
    __shared__ int base[512];
    int t = threadIdx.x;
    for (int i = t; i < nbins; i += 256) h[i] = 0;
    __syncthreads();
    int eb = blockIdx.x * EPB;
    int ss[16], ds[16];
#pragma unroll
    for (int i = 0; i < 16; ++i) {
        int e = eb + t + i * 256;
        if (e < ne) { ss[i] = src[e]; ds[i] = dst[e]; atomicAdd(&h[ds[i] >> 8], 1); }
        else ds[i] = -1;
    }
    __syncthreads();
    for (int i = t; i < nbins; i += 256) base[i] = h[i] ? atomicAdd(&binCur[i], h[i]) : 0;
    __syncthreads();
    for (int i = t; i < nbins; i += 256) h[i] = 0;   // reuse as local cursor
    __syncthreads();
#pragma unroll
    for (int i = 0; i < 16; ++i) {
        if (ds[i] >= 0) {
            int b = ds[i] >> 8;
            int p = atomicAdd(&h[b], 1);
            part[base[b] + p] = ((unsigned)ss[i] << 8) | (unsigned)(ds[i] & 255);
        }
    }
}

__global__ __launch_bounds__(256) void bin_finalize(const unsigned* __restrict__ part,
                                                    const int* __restrict__ binOff,
                                                    int* __restrict__ off, int* __restrict__ perm,
                                                    int n, int nbins) {
    __shared__ unsigned st[CAP];
    __shared__ int cnt[256], ex[256], cur[256];
    int b = blockIdx.x;
    int t = threadIdx.x;
    int e0 = binOff[b], e1 = binOff[b + 1];
    int m = e1 - e0;
    int nb0 = b << 8;
    int nn = min(256, n - nb0);
    cnt[t] = 0;
    __syncthreads();
    bool staged = (m <= CAP);
    if (staged) {
        for (int i = t; i < m; i += 256) { unsigned v = part[e0 + i]; st[i] = v; atomicAdd(&cnt[v & 255u], 1); }
    } else {
        for (int i = t; i < m; i += 256) { unsigned v = part[e0 + i]; atomicAdd(&cnt[v & 255u], 1); }
    }
    __syncthreads();
    int v = cnt[t];
    ex[t] = v;
    __syncthreads();
    for (int o = 1; o < 256; o <<= 1) {
        int u = (t >= o) ? ex[t - o] : 0;
        __syncthreads();
        ex[t] += u;
        __syncthreads();
    }
    int excl = ex[t] - v;
    if (t < nn) off[nb0 + t] = e0 + excl;
    cur[t] = excl;
    __syncthreads();
    if (staged) {
        for (int i = t; i < m; i += 256) {
            unsigned w = st[i];
            int p = atomicAdd(&cur[w & 255u], 1);
            perm[e0 + p] = (int)(w >> 8);
        }
    } else {
        for (int i = t; i < m; i += 256) {
            unsigned w = part[e0 + i];
            int p = atomicAdd(&cur[w & 255u], 1);
            perm[e0 + p] = (int)(w >> 8);
        }
    }
}

// acc = bf16_table[self] + sum_{e in CSR(i)} bf16_table[perm[e]]
// 16 lanes/node, 16 nodes/block; 16-deep then 8-deep then scalar edge batches.
#define GATHER_BODY                                                               \
    int t = threadIdx.x;                                                          \
    int node = blockIdx.x * 16 + (t >> 4);                                        \
    int c = t & 15;                                                               \
    if (node >= n) return;                                                        \
    int beg = off[node], end = off[node + 1];                                     \
    uint2 sv = xh[(size_t)node * 16 + c];                                         \
    float4 acc = make_float4(bl(sv.x), bh(sv.x), bl(sv.y), bh(sv.y));             \
    int e = beg;                                                                  \
    for (; e + 16 <= end; e += 16) {                                              \
        uint2 v[16];                                                              \
        _Pragma("unroll")                                                         \
        for (int j = 0; j < 16; ++j) v[j] = xh[(size_t)perm[e + j] * 16 + c];     \
        _Pragma("unroll")                                                         \
        for (int j = 0; j < 16; ++j) {                                            \
            acc.x += bl(v[j].x); acc.y += bh(v[j].x);                             \
            acc.z += bl(v[j].y); acc.w += bh(v[j].y);                             \
        }                                                                         \
    }                                                                             \
    for (; e + 8 <= end; e += 8) {                                                \
        uint2 v[8];                                                               \
        _Pragma("unroll")                                                         \
        for (int j = 0; j < 8; ++j) v[j] = xh[(size_t)perm[e + j] * 16 + c];      \
        _Pragma("unroll")                                                         \
        for (int j = 0; j < 8; ++j) {                                             \
            acc.x += bl(v[j].x); acc.y += bh(v[j].x);                             \
            acc.z += bl(v[j].y); acc.w += bh(v[j].y);                             \
        }                                                                         \
    }                                                                             \
    for (; e < end; ++e) {                                                        \
        uint2 v = xh[(size_t)perm[e] * 16 + c];                                   \
        acc.x += bl(v.x); acc.y += bh(v.x); acc.z += bl(v.y); acc.w += bh(v.y);   \
    }

// layer 1: emit bf16 (feeds MFMA A-fragments)
__global__ __launch_bounds__(256) void gather_l1(const uint2* __restrict__ xh,
                                                 const int* __restrict__ off,
                                                 const int* __restrict__ perm,
                                                 uint2* __restrict__ outh, int n) {
    GATHER_BODY
    outh[(size_t)node * 16 + c] = make_uint2(pk(acc.x, acc.y), pk(acc.z, acc.w));
}

// layer 2: emit f32 with bias (the final output)
__global__ __launch_bounds__(256) void gather_l2(const uint2* __restrict__ xh,
                                                 const float* __restrict__ bias,
                                                 const int* __restrict__ off,
                                                 const int* __restrict__ perm,
                                                 float4* __restrict__ out4, int n) {
    GATHER_BODY
    float4 bb = reinterpret_cast<const float4*>(bias)[c];
    acc.x += bb.x; acc.y += bb.y; acc.z += bb.z; acc.w += bb.w;
    out4[(size_t)node * 16 + c] = acc;
}

// Fused MLP via MFMA 16x16x32 bf16. 4 waves, 128 rows/block, 32 rows/wave.
// Phase 1: h=relu(A@W1+b1) -> LDS bf16 (wave-private rows, no __syncthreads).
// Phase 2: gh = bf16(h@W2). b2 is applied by gather_l2.
// Fragment layouts (guide m89-verified): A: row=l&15, k=(l>>4)*8+j;
// B: col=l&15, k=(l>>4)*8+j (W stored transposed [col][k]);
// D: col=l&15, row=(l>>4)*4+reg.
__global__ __launch_bounds__(256) void mlp_fused(const unsigned short* __restrict__ ah,
                                                 const unsigned short* __restrict__ w1t,
                                                 const float* __restrict__ b1,
                                                 const unsigned short* __restrict__ w2t,
                                                 unsigned short* __restrict__ gh, int n) {
    __shared__ unsigned short hl[128][LDST];   // 34.8 KiB
    int t = threadIdx.x;
    int w = t >> 6;
    int l = t & 63;
    int lr = l & 15;
    int lg = l >> 4;
    int row0 = blockIdx.x * 128 + w * 32;

    // ---- phase 1: h = relu(agg1h @ W1 + b1) -> LDS ----
    bf16x8 b1f[8][2];
#pragma unroll
    for (int ct = 0; ct < 8; ++ct)
#pragma unroll
        for (int kc = 0; kc < 2; ++kc)
            b1f[ct][kc] = *reinterpret_cast<const bf16x8*>(
                w1t + (size_t)(ct * 16 + lr) * 64 + kc * 32 + lg * 8);
    float bias1[8];
#pragma unroll
    for (int ct = 0; ct < 8; ++ct) bias1[ct] = b1[ct * 16 + lr];

#pragma unroll
    for (int rt = 0; rt < 2; ++rt) {
        int arow = row0 + rt * 16 + lr;
        if (arow > n - 1) arow = n - 1;
        bf16x8 a0 = *reinterpret_cast<const bf16x8*>(ah + (size_t)arow * 64 + lg * 8);
        bf16x8 a1 = *reinterpret_cast<const bf16x8*>(ah + (size_t)arow * 64 + 32 + lg * 8);
        int lrow = w * 32 + rt * 16 + lg * 4;
#pragma unroll
        for (int ct = 0; ct < 8; ++ct) {
            f32x4 acc = {0.f, 0.f, 0.f, 0.f};
            acc = __builtin_amdgcn_mfma_f32_16x16x32_bf16(a0, b1f[ct][0], acc, 0, 0, 0);
            acc = __builtin_amdgcn_mfma_f32_16x16x32_bf16(a1, b1f[ct][1], acc, 0, 0, 0);
#pragma unroll
            for (int r = 0; r < 4; ++r) {
                float v = fmaxf(acc[r] + bias1[ct], 0.f);
                hl[lrow + r][ct * 16 + lr] = f2b(v);
            }
        }
    }

    // ---- phase 2: g = h @ W2 (same-wave LDS reuse; compiler inserts waits) ----
    bf16x8 b2f[4][4];
#pragma unroll
    for (int ct = 0; ct < 4; ++ct)
#pragma unroll
        for (int kc = 0; kc < 4; ++kc)
            b2f[ct][kc] = *reinterpret_cast<const bf16x8*>(
                w2t + (size_t)(ct * 16 + lr) * 128 + kc * 32 + lg * 8);

#pragma unroll
    for (int rt = 0; rt < 2; ++rt) {
        int lrow = w * 32 + rt * 16 + lr;
        f32x4 acc[4];
#pragma unroll
        for (int ct = 0; ct < 4; ++ct) acc[ct] = (f32x4){0.f, 0.f, 0.f, 0.f};
#pragma unroll
        for (int kc = 0; kc < 4; ++kc) {
            bf16x8 a = *reinterpret_cast<const bf16x8*>(&hl[lrow][kc * 32 + lg * 8]);
#pragma unroll
            for (int ct = 0; ct < 4; ++ct)
                acc[ct] = __builtin_amdgcn_mfma_f32_16x16x32_bf16(a, b2f[ct][kc], acc[ct], 0, 0, 0);
        }
        int orow = row0 + rt * 16 + lg * 4;
#pragma unroll
        for (int ct = 0; ct < 4; ++ct) {
#pragma unroll
            for (int r = 0; r < 4; ++r) {
                int row = orow + r;
                if (row < n) gh[(size_t)row * 64 + ct * 16 + lr] = f2b(acc[ct][r]);
            }
        }
    }
}

extern "C" void kernel_launch(void* const* d_in, const int* in_sizes, int n_in,
                              void* d_out, int out_size, void* d_ws, size_t ws_size,
                              hipStream_t stream) {
    const float* node_emb = (const float*)d_in[0];
    const float* W1 = (const float*)d_in[1];
    const float* b1 = (const float*)d_in[2];
    const float* W2 = (const float*)d_in[3];
    const float* b2 = (const float*)d_in[4];
    const int*   ei = (const int*)d_in[5];
    int n  = in_sizes[0] / 64;
    int ne = in_sizes[5] / 2;
    const int* src = ei;
    const int* dst = ei + ne;
    float* out = (float*)d_out;

    int nbins = (n + 255) >> 8;   // 391

    // workspace layout (~56 MB, no aliasing)
    char* ws = (char*)d_ws;
    const size_t MB = 1024 * 1024;
    uint2*          agg1h = (uint2*)ws;                          // n*64 bf16 (12.8 MB)
    uint2*          gh    = (uint2*)(ws + 13 * MB);              // n*64 bf16 (12.8 MB)
    uint2*          xh    = (uint2*)(ws + 26 * MB);              // n*64 bf16 (12.8 MB)
    unsigned*       part  = (unsigned*)(ws + 39 * MB);           // ne u32 (6.4 MB)
    unsigned short* w1t   = (unsigned short*)(ws + 46 * MB);     // 16 KB
    unsigned short* w2t   = (unsigned short*)(ws + 46 * MB + 65536);
    int* off    = (int*)(ws + 47 * MB);                          // (n+1)*4
    int* perm   = (int*)(ws + 48 * MB);                          // ne*4 (6.4 MB)
    int* binCnt = (int*)(ws + 55 * MB);
    int* binOff = (int*)(ws + 55 * MB + 4096);
    int* binCur = (int*)(ws + 55 * MB + 8192);

    int nCvt  = (n * 16 + 255) / 256;          // 6250
    int nHist = (ne + EPB - 1) / EPB;          // 391

    prep<<<66, 256, 0, stream>>>(W1, W2, w1t, w2t, binCnt);
    cvt_hist<<<nCvt + nHist, 256, 0, stream>>>((const float4*)node_emb, xh, n * 16,
                                               dst, binCnt, ne, nbins, nCvt);
    scan_bins<<<1, 512, 0, stream>>>(binCnt, binOff, binCur, off, nbins, n, ne);
    partition<<<nHist, 256, 0, stream>>>(src, dst, binCur, part, ne, nbins);
    bin_finalize<<<nbins, 256, 0, stream>>>(part, binOff, off, perm, n, nbins);

    gather_l1<<<(n + 15) / 16, 256, 0, stream>>>(xh, off, perm, agg1h, n);
    mlp_fused<<<(n + 127) / 128, 256, 0, stream>>>((const unsigned short*)agg1h, w1t, b1,
                                                   w2t, (unsigned short*)gh, n);
    gather_l2<<<(n + 15) / 16, 256, 0, stream>>>(gh, b2, off, perm, (float4*)out, n);
}

// Round 14
// 159.596 us; speedup vs baseline: 1.3046x; 1.0800x over previous
//
#include <hip/hip_runtime.h>

// GIN 2-layer forward — CSR counting sort + bf16/fp8 gather tables + fused MFMA MLP.
// Pipeline (8 dispatches):
//   prep:      w1t/w2t bf16 transposed tables + zero binCnt
//   cvt_hist:  xh = bf16(node_emb)  ||  LDS-histogram dst>>8   (grid-partitioned)
//   scan_bins -> partition (EPB 4096, 16-reg cache) -> bin_finalize
//   agg1h = bf16( xh[self] + gather(xh) )        [gather_l1, 16/8-deep, bf16]
//   mlp_fused: h = relu(agg1h@W1+b1) in LDS; gq = fp8e4m3(h@W2)  [MFMA 16x16x32]
//   out = b2 + fp8(gq[self]) + gather_fp8(gq)    [gather_l2]
// (W2 folded before aggregation-2: (A h + h) W2 + b2 = A(hW2) + hW2 + b2.)
// R6: gather cache-BW bound -> bf16 tables. R7-R9: f32 vector GEMM trapped ->
// MFMA. R11: occupancy > write-run length. R12 analysis: gather_l2's L2 misses
// are ~100% compulsory-per-XCD (84MB fetch ~= 8 XCD x touched table) and
// MSHR x L3-latency bound -> fp8 table halves lines touched (-43% misses).
// R13 lesson: cvt_f32_fp8's sel operand must be an ICE -> template<int SEL>.

#define EPB 4096      // edges per hist/partition block
#define CAP 6144      // LDS staging cap in bin_finalize
#define LDST 136      // LDS h row stride in u16 (272 B, 16B-aligned)

typedef __attribute__((ext_vector_type(8))) short bf16x8;
typedef __attribute__((ext_vector_type(4))) float f32x4;

__device__ __forceinline__ unsigned short f2b(float f) {   // RNE f32->bf16
    unsigned u = __float_as_uint(f);
    return (unsigned short)((u + 0x7fffu + ((u >> 16) & 1u)) >> 16);
}
__device__ __forceinline__ unsigned pk(float a, float b) {
    return (unsigned)f2b(a) | ((unsigned)f2b(b) << 16);
}
__device__ __forceinline__ float bl(unsigned u) { return __uint_as_float(u << 16); }
__device__ __forceinline__ float bh(unsigned u) { return __uint_as_float(u & 0xffff0000u); }

// ---- fp8 e4m3fn encode/decode: HW cvt when available, SW fallback otherwise ----
#if __has_builtin(__builtin_amdgcn_cvt_f32_fp8) && __has_builtin(__builtin_amdgcn_cvt_pk_fp8_f32)
#define HW_FP8 1
#endif

__device__ __forceinline__ unsigned char f2fp8(float f) {
#ifdef HW_FP8
    return (unsigned char)(__builtin_amdgcn_cvt_pk_fp8_f32(f, f, 0, 0) & 0xff);
#else
    unsigned u = __float_as_uint(f);
    unsigned s = (u >> 24) & 0x80u;
    unsigned a = u & 0x7fffffffu;
    if (a >= 0x43e00000u) return (unsigned char)(s | 0x7eu);   // clamp to 448
    if (a < 0x3c800000u) return (unsigned char)s;              // <2^-6: flush to 0
    unsigned lsb = (a >> 20) & 1u;
    a += 0x7ffffu + lsb;                                       // RNE to 3-bit mantissa
    unsigned e = (a >> 23) - 120u;
    unsigned m = (a >> 20) & 7u;
    return (unsigned char)(s | (e << 3) | m);
#endif
}

template <int SEL>
__device__ __forceinline__ float fp8f(unsigned v) {   // decode byte SEL (ICE)
#ifdef HW_FP8
    return __builtin_amdgcn_cvt_f32_fp8(v, SEL);
#else
    unsigned b = (v >> (SEL * 8)) & 0xffu;
    unsigned s = (b & 0x80u) << 24;
    unsigned em = b & 0x7fu;
    unsigned f = s | ((em + 960u) << 20);
    return __uint_as_float(em ? f : s);
#endif
}

// W1t [128c][64k] bf16, W2t [64c][128k] bf16, zero binCnt. grid 66x256.
__global__ void prep(const float* __restrict__ W1, const float* __restrict__ W2,
                     unsigned short* __restrict__ w1t, unsigned short* __restrict__ w2t,
                     int* __restrict__ binCnt) {
    int i = blockIdx.x * 256 + threadIdx.x;
    if (i < 8192) {
        int c = i >> 6, k = i & 63;
        w1t[i] = f2b(W1[k * 128 + c]);
    } else if (i < 16384) {
        int j = i - 8192;
        int c = j >> 7, k = j & 127;
        w2t[j] = f2b(W2[k * 64 + c]);
    } else if (i < 16384 + 512) {
        binCnt[i - 16384] = 0;
    }
}

// blocks [0,nCvt): xh = bf16(x). blocks [nCvt, nCvt+nHist): LDS hist of dst>>8.
__global__ __launch_bounds__(256) void cvt_hist(const float4* __restrict__ x4,
                                                uint2* __restrict__ xh, int n16,
                                                const int* __restrict__ dst,
                                                int* __restrict__ binCnt,
                                                int ne, int nbins, int nCvt) {
    if ((int)blockIdx.x < nCvt) {
        int i = blockIdx.x * 256 + threadIdx.x;
        if (i < n16) {
            float4 v = x4[i];
            xh[i] = make_uint2(pk(v.x, v.y), pk(v.z, v.w));
        }
        return;
    }
    __shared__ int h[512];
    int t = threadIdx.x;
    for (int i = t; i < nbins; i += 256) h[i] = 0;
    __syncthreads();
    int eb = ((int)blockIdx.x - nCvt) * EPB;
#pragma unroll
    for (int i = 0; i < 16; ++i) {
        int e = eb + t + i * 256;
        if (e < ne) atomicAdd(&h[dst[e] >> 8], 1);
    }
    __syncthreads();
    for (int i = t; i < nbins; i += 256) if (h[i]) atomicAdd(&binCnt[i], h[i]);
}

__global__ __launch_bounds__(512) void scan_bins(const int* __restrict__ binCnt,
                                                 int* __restrict__ binOff, int* __restrict__ binCur,
                                                 int* __restrict__ off, int nbins, int n, int ne) {
    __shared__ int s[512];
    int t = threadIdx.x;
    int v = (t < nbins) ? binCnt[t] : 0;
    s[t] = v;
    __syncthreads();
    for (int o = 1; o < 512; o <<= 1) {
        int u = (t >= o) ? s[t - o] : 0;
        __syncthreads();
        s[t] += u;
        __syncthreads();
    }
    if (t < nbins) { int b = s[t] - v; binOff[t] = b; binCur[t] = b; }
    if (t == 0) { binOff[nbins] = ne; off[n] = ne; }
}

// 16 edges/thread cached in regs; LDS hist; one global atomic per nonzero bin
// per block; LDS-cursor scatter of packed (src<<8|dstLocal).
__global__ __launch_bounds__(256) void partition(const int* __restrict__ src,
                                                 const int* __restrict__ dst,
                                                 int* __restrict__ binCur,
                                                 unsigned* __restrict__ part, int ne, int nbins) {
    __shared__ int h[512];
    __shared__ int base[512];
    int t = threadIdx.x;
    for (int i = t; i < nbins; i += 256) h[i] = 0;
    __syncthreads();
    int eb = blockIdx.x * EPB;
    int ss[16], ds[16];
#pragma unroll
    for (int i = 0; i < 16; ++i) {
        int e = eb + t + i * 256;
        if (e < ne) { ss[i] = src[e]; ds[i] = dst[e]; atomicAdd(&h[ds[i] >> 8], 1); }
        else ds[i] = -1;
    }
    __syncthreads();
    for (int i = t; i < nbins; i += 256) base[i] = h[i] ? atomicAdd(&binCur[i], h[i]) : 0;
    __syncthreads();
    for (int i = t; i < nbins; i += 256) h[i] = 0;   // reuse as local cursor
    __syncthreads();
#pragma unroll
    for (int i = 0; i < 16; ++i) {
        if (ds[i] >= 0) {
            int b = ds[i] >> 8;
            int p = atomicAdd(&h[b], 1);
            part[base[b] + p] = ((unsigned)ss[i] << 8) | (unsigned)(ds[i] & 255);
        }
    }
}

__global__ __launch_bounds__(256) void bin_finalize(const unsigned* __restrict__ part,
                                                    const int* __restrict__ binOff,
                                                    int* __restrict__ off, int* __restrict__ perm,
                                                    int n, int nbins) {
    __shared__ unsigned st[CAP];
    __shared__ int cnt[256], ex[256], cur[256];
    int b = blockIdx.x;
    int t = threadIdx.x;
    int e0 = binOff[b], e1 = binOff[b + 1];
    int m = e1 - e0;
    int nb0 = b << 8;
    int nn = min(256, n - nb0);
    cnt[t] = 0;
    __syncthreads();
    bool staged = (m <= CAP);
    if (staged) {
        for (int i = t; i < m; i += 256) { unsigned v = part[e0 + i]; st[i] = v; atomicAdd(&cnt[v & 255u], 1); }
    } else {
        for (int i = t; i < m; i += 256) { unsigned v = part[e0 + i]; atomicAdd(&cnt[v & 255u], 1); }
    }
    __syncthreads();
    int v = cnt[t];
    ex[t] = v;
    __syncthreads();
    for (int o = 1; o < 256; o <<= 1) {
        int u = (t >= o) ? ex[t - o] : 0;
        __syncthreads();
        ex[t] += u;
        __syncthreads();
    }
    int excl = ex[t] - v;
    if (t < nn) off[nb0 + t] = e0 + excl;
    cur[t] = excl;
    __syncthreads();
    if (staged) {
        for (int i = t; i < m; i += 256) {
            unsigned w = st[i];
            int p = atomicAdd(&cur[w & 255u], 1);
            perm[e0 + p] = (int)(w >> 8);
        }
    } else {
        for (int i = t; i < m; i += 256) {
            unsigned w = part[e0 + i];
            int p = atomicAdd(&cur[w & 255u], 1);
            perm[e0 + p] = (int)(w >> 8);
        }
    }
}

// layer-1 gather (bf16 table): acc = xh[self] + sum xh[perm[e]]; emit bf16.
__global__ __launch_bounds__(256) void gather_l1(const uint2* __restrict__ xh,
                                                 const int* __restrict__ off,
                                                 const int* __restrict__ perm,
                                                 uint2* __restrict__ outh, int n) {
    int t = threadIdx.x;
    int node = blockIdx.x * 16 + (t >> 4);
    int c = t & 15;
    if (node >= n) return;
    int beg = off[node], end = off[node + 1];
    uint2 sv = xh[(size_t)node * 16 + c];
    float4 acc = make_float4(bl(sv.x), bh(sv.x), bl(sv.y), bh(sv.y));
    int e = beg;
    for (; e + 16 <= end; e += 16) {
        uint2 v[16];
#pragma unroll
        for (int j = 0; j < 16; ++j) v[j] = xh[(size_t)perm[e + j] * 16 + c];
#pragma unroll
        for (int j = 0; j < 16; ++j) {
            acc.x += bl(v[j].x); acc.y += bh(v[j].x);
            acc.z += bl(v[j].y); acc.w += bh(v[j].y);
        }
    }
    for (; e + 8 <= end; e += 8) {
        uint2 v[8];
#pragma unroll
        for (int j = 0; j < 8; ++j) v[j] = xh[(size_t)perm[e + j] * 16 + c];
#pragma unroll
        for (int j = 0; j < 8; ++j) {
            acc.x += bl(v[j].x); acc.y += bh(v[j].x);
            acc.z += bl(v[j].y); acc.w += bh(v[j].y);
        }
    }
    for (; e < end; ++e) {
        uint2 v = xh[(size_t)perm[e] * 16 + c];
        acc.x += bl(v.x); acc.y += bh(v.x); acc.z += bl(v.y); acc.w += bh(v.y);
    }
    outh[(size_t)node * 16 + c] = make_uint2(pk(acc.x, acc.y), pk(acc.z, acc.w));
}

// layer-2 gather (fp8 table, 64 B rows): out = b2 + gq[self] + sum gq[perm[e]].
__global__ __launch_bounds__(256) void gather_l2(const unsigned* __restrict__ gq,
                                                 const float* __restrict__ bias,
                                                 const int* __restrict__ off,
                                                 const int* __restrict__ perm,
                                                 float4* __restrict__ out4, int n) {
    int t = threadIdx.x;
    int node = blockIdx.x * 16 + (t >> 4);
    int c = t & 15;               // uint c = channels 4c..4c+3
    if (node >= n) return;
    int beg = off[node], end = off[node + 1];
    unsigned sv = gq[(size_t)node * 16 + c];
    float4 acc = make_float4(fp8f<0>(sv), fp8f<1>(sv), fp8f<2>(sv), fp8f<3>(sv));
    int e = beg;
    for (; e + 16 <= end; e += 16) {
        unsigned v[16];
#pragma unroll
        for (int j = 0; j < 16; ++j) v[j] = gq[(size_t)perm[e + j] * 16 + c];
#pragma unroll
        for (int j = 0; j < 16; ++j) {
            acc.x += fp8f<0>(v[j]); acc.y += fp8f<1>(v[j]);
            acc.z += fp8f<2>(v[j]); acc.w += fp8f<3>(v[j]);
        }
    }
    for (; e + 8 <= end; e += 8) {
        unsigned v[8];
#pragma unroll
        for (int j = 0; j < 8; ++j) v[j] = gq[(size_t)perm[e + j] * 16 + c];
#pragma unroll
        for (int j = 0; j < 8; ++j) {
            acc.x += fp8f<0>(v[j]); acc.y += fp8f<1>(v[j]);
            acc.z += fp8f<2>(v[j]); acc.w += fp8f<3>(v[j]);
        }
    }
    for (; e < end; ++e) {
        unsigned v = gq[(size_t)perm[e] * 16 + c];
        acc.x += fp8f<0>(v); acc.y += fp8f<1>(v);
        acc.z += fp8f<2>(v); acc.w += fp8f<3>(v);
    }
    float4 bb = reinterpret_cast<const float4*>(bias)[c];
    acc.x += bb.x; acc.y += bb.y; acc.z += bb.z; acc.w += bb.w;
    out4[(size_t)node * 16 + c] = acc;
}

// Fused MLP via MFMA 16x16x32 bf16. 4 waves, 128 rows/block, 32 rows/wave.
// Phase 1: h=relu(A@W1+b1) -> LDS bf16 (wave-private rows, no __syncthreads).
// Phase 2: gq = fp8_e4m3(h@W2). b2 is applied by gather_l2.
// Fragment layouts (guide m89-verified): A: row=l&15, k=(l>>4)*8+j;
// B: col=l&15, k=(l>>4)*8+j (W stored transposed [col][k]);
// D: col=l&15, row=(l>>4)*4+reg.
__global__ __launch_bounds__(256) void mlp_fused(const unsigned short* __restrict__ ah,
                                                 const unsigned short* __restrict__ w1t,
                                                 const float* __restrict__ b1,
                                                 const unsigned short* __restrict__ w2t,
                                                 unsigned char* __restrict__ gq, int n) {
    __shared__ unsigned short hl[128][LDST];   // 34.8 KiB
    int t = threadIdx.x;
    int w = t >> 6;
    int l = t & 63;
    int lr = l & 15;
    int lg = l >> 4;
    int row0 = blockIdx.x * 128 + w * 32;

    // ---- phase 1: h = relu(agg1h @ W1 + b1) -> LDS ----
    bf16x8 b1f[8][2];
#pragma unroll
    for (int ct = 0; ct < 8; ++ct)
#pragma unroll
        for (int kc = 0; kc < 2; ++kc)
            b1f[ct][kc] = *reinterpret_cast<const bf16x8*>(
                w1t + (size_t)(ct * 16 + lr) * 64 + kc * 32 + lg * 8);
    float bias1[8];
#pragma unroll
    for (int ct = 0; ct < 8; ++ct) bias1[ct] = b1[ct * 16 + lr];

#pragma unroll
    for (int rt = 0; rt < 2; ++rt) {
        int arow = row0 + rt * 16 + lr;
        if (arow > n - 1) arow = n - 1;
        bf16x8 a0 = *reinterpret_cast<const bf16x8*>(ah + (size_t)arow * 64 + lg * 8);
        bf16x8 a1 = *reinterpret_cast<const bf16x8*>(ah + (size_t)arow * 64 + 32 + lg * 8);
        int lrow = w * 32 + rt * 16 + lg * 4;
#pragma unroll
        for (int ct = 0; ct < 8; ++ct) {
            f32x4 acc = {0.f, 0.f, 0.f, 0.f};
            acc = __builtin_amdgcn_mfma_f32_16x16x32_bf16(a0, b1f[ct][0], acc, 0, 0, 0);
            acc = __builtin_amdgcn_mfma_f32_16x16x32_bf16(a1, b1f[ct][1], acc, 0, 0, 0);
#pragma unroll
            for (int r = 0; r < 4; ++r) {
                float v = fmaxf(acc[r] + bias1[ct], 0.f);
                hl[lrow + r][ct * 16 + lr] = f2b(v);
            }
        }
    }

    // ---- phase 2: g = h @ W2 -> fp8 table (same-wave LDS reuse) ----
    bf16x8 b2f[4][4];
#pragma unroll
    for (int ct = 0; ct < 4; ++ct)
#pragma unroll
        for (int kc = 0; kc < 4; ++kc)
            b2f[ct][kc] = *reinterpret_cast<const bf16x8*>(
                w2t + (size_t)(ct * 16 + lr) * 128 + kc * 32 + lg * 8);

#pragma unroll
    for (int rt = 0; rt < 2; ++rt) {
        int lrow = w * 32 + rt * 16 + lr;
        f32x4 acc[4];
#pragma unroll
        for (int ct = 0; ct < 4; ++ct) acc[ct] = (f32x4){0.f, 0.f, 0.f, 0.f};
#pragma unroll
        for (int kc = 0; kc < 4; ++kc) {
            bf16x8 a = *reinterpret_cast<const bf16x8*>(&hl[lrow][kc * 32 + lg * 8]);
#pragma unroll
            for (int ct = 0; ct < 4; ++ct)
                acc[ct] = __builtin_amdgcn_mfma_f32_16x16x32_bf16(a, b2f[ct][kc], acc[ct], 0, 0, 0);
        }
        int orow = row0 + rt * 16 + lg * 4;
#pragma unroll
        for (int ct = 0; ct < 4; ++ct) {
#pragma unroll
            for (int r = 0; r < 4; ++r) {
                int row = orow + r;
                if (row < n) gq[(size_t)row * 64 + ct * 16 + lr] = f2fp8(acc[ct][r]);
            }
        }
    }
}

extern "C" void kernel_launch(void* const* d_in, const int* in_sizes, int n_in,
                              void* d_out, int out_size, void* d_ws, size_t ws_size,
                              hipStream_t stream) {
    const float* node_emb = (const float*)d_in[0];
    const float* W1 = (const float*)d_in[1];
    const float* b1 = (const float*)d_in[2];
    const float* W2 = (const float*)d_in[3];
    const float* b2 = (const float*)d_in[4];
    const int*   ei = (const int*)d_in[5];
    int n  = in_sizes[0] / 64;
    int ne = in_sizes[5] / 2;
    const int* src = ei;
    const int* dst = ei + ne;
    float* out = (float*)d_out;

    int nbins = (n + 255) >> 8;   // 391

    // workspace layout (~56 MB, no aliasing)
    char* ws = (char*)d_ws;
    const size_t MB = 1024 * 1024;
    uint2*          agg1h = (uint2*)ws;                          // n*64 bf16 (12.8 MB)
    unsigned char*  gq    = (unsigned char*)(ws + 13 * MB);      // n*64 fp8 (6.4 MB)
    uint2*          xh    = (uint2*)(ws + 26 * MB);              // n*64 bf16 (12.8 MB)
    unsigned*       part  = (unsigned*)(ws + 39 * MB);           // ne u32 (6.4 MB)
    unsigned short* w1t   = (unsigned short*)(ws + 46 * MB);     // 16 KB
    unsigned short* w2t   = (unsigned short*)(ws + 46 * MB + 65536);
    int* off    = (int*)(ws + 47 * MB);                          // (n+1)*4
    int* perm   = (int*)(ws + 48 * MB);                          // ne*4 (6.4 MB)
    int* binCnt = (int*)(ws + 55 * MB);
    int* binOff = (int*)(ws + 55 * MB + 4096);
    int* binCur = (int*)(ws + 55 * MB + 8192);

    int nCvt  = (n * 16 + 255) / 256;          // 6250
    int nHist = (ne + EPB - 1) / EPB;          // 391

    prep<<<66, 256, 0, stream>>>(W1, W2, w1t, w2t, binCnt);
    cvt_hist<<<nCvt + nHist, 256, 0, stream>>>((const float4*)node_emb, xh, n * 16,
                                               dst, binCnt, ne, nbins, nCvt);
    scan_bins<<<1, 512, 0, stream>>>(binCnt, binOff, binCur, off, nbins, n, ne);
    partition<<<nHist, 256, 0, stream>>>(src, dst, binCur, part, ne, nbins);
    bin_finalize<<<nbins, 256, 0, stream>>>(part, binOff, off, perm, n, nbins);

    gather_l1<<<(n + 15) / 16, 256, 0, stream>>>(xh, off, perm, agg1h, n);
    mlp_fused<<<(n + 127) / 128, 256, 0, stream>>>((const unsigned short*)agg1h, w1t, b1,
                                                   w2t, gq, n);
    gather_l2<<<(n + 15) / 16, 256, 0, stream>>>((const unsigned*)gq, b2, off, perm,
                                                 (float4*)out, n);
}